// Round 13
// baseline (76.129 us; speedup 1.0000x reference)
//
#include <hip/hip_runtime.h>
#include <hip/hip_bf16.h>

typedef unsigned short u16;
typedef unsigned int u32;
typedef unsigned long long u64;
typedef __attribute__((ext_vector_type(8))) short bf16x8;
typedef __attribute__((ext_vector_type(4))) float f32x4;
typedef __attribute__((ext_vector_type(4))) u16 u16x4;

#define N 4096
#define F 128
#define H 4
#define O 64
#define NW (N / 64)   // 64-bit words per adjacency row
#define NT 16         // KV tiles per column-half per z-slice (1024/64)
// log2(e)/8: folds the /sqrt(64) and the exp->exp2 conversion into Q.
#define QSCALE 0.18033688011112043f

__device__ inline float exp2_hw(float x) {
#if __has_builtin(__builtin_amdgcn_exp2f)
  return __builtin_amdgcn_exp2f(x);      // v_exp_f32, hazards handled by compiler
#else
  return __expf(x * 0.6931471805599453f);
#endif
}

__device__ inline u16 f2bf(float f) {           // RNE convert
  union { __hip_bfloat16 b; u16 u; } v;
  v.b = __float2bfloat16(f);
  return v.u;
}

// ---------------------------------------------------------------------------
// Fused prep: [0,1024) pack | [1024,1792) proj | [1792,1808) mask.
// ---------------------------------------------------------------------------
__global__ __launch_bounds__(256) void prep_kernel(
    const float* __restrict__ x, const float* __restrict__ adj,
    const float* __restrict__ wv, const float* __restrict__ wq,
    const float* __restrict__ wk, u16* __restrict__ Q, u16* __restrict__ K,
    u16* __restrict__ Vt, float* __restrict__ rmask, u64* __restrict__ bits) {
  const int b = blockIdx.x;
  const int t = threadIdx.x;

  if (b < 1024) {
    // ---- pack: adjacency (0/1 fp32) -> bitmask ----
    const int w = t >> 6, l = t & 63;
    const int row = b * 4 + w;
    const float* ar = adj + (size_t)row * N;
    u64* br = bits + (size_t)row * NW;
#pragma unroll 4
    for (int j2 = 0; j2 < 16; j2++) {
      float4 v = *(const float4*)&ar[j2 * 256 + l * 4];
      unsigned nib = (unsigned)(v.x != 0.f) | ((unsigned)(v.y != 0.f) << 1) |
                     ((unsigned)(v.z != 0.f) << 2) | ((unsigned)(v.w != 0.f) << 3);
      u64 word = (u64)nib << ((l & 15) * 4);
      word |= __shfl_xor(word, 1);
      word |= __shfl_xor(word, 2);
      word |= __shfl_xor(word, 4);
      word |= __shfl_xor(word, 8);
      if ((l & 15) == 0) br[j2 * 4 + (l >> 4)] = word;
    }
  } else if (b < 1792) {
    // ---- proj: fp32 GEMM, outputs bf16 (Q pre-scaled by QSCALE) ----
    __shared__ float xs[64][132];
    __shared__ float wsh[128][64];
    const int pb = b - 1024;
    const int brow = (pb & 63) * 64;
    const int p = pb >> 6, h = p / 3, which = p % 3;
    const float* W = (which == 0 ? wq : which == 1 ? wk : wv) + h * F * O;

#pragma unroll
    for (int i = 0; i < 8; i++) {
      int idx = t + i * 256, r = idx >> 5, c4 = idx & 31;
      *(float4*)&xs[r][c4 * 4] = *(const float4*)&x[(brow + r) * F + c4 * 4];
    }
#pragma unroll
    for (int i = 0; i < 8; i++) {
      int idx = t + i * 256, r = idx >> 4, c4 = idx & 15;
      *(float4*)&wsh[r][c4 * 4] = *(const float4*)&W[r * O + c4 * 4];
    }
    __syncthreads();

    const int r0 = (t >> 4) << 2, c0 = (t & 15) << 2;
    float acc[4][4] = {};
#pragma unroll 8
    for (int f = 0; f < F; f++) {
      float4 bb = *(float4*)&wsh[f][c0];
      float a0 = xs[r0 + 0][f], a1 = xs[r0 + 1][f];
      float a2 = xs[r0 + 2][f], a3 = xs[r0 + 3][f];
      acc[0][0] = fmaf(a0, bb.x, acc[0][0]); acc[0][1] = fmaf(a0, bb.y, acc[0][1]);
      acc[0][2] = fmaf(a0, bb.z, acc[0][2]); acc[0][3] = fmaf(a0, bb.w, acc[0][3]);
      acc[1][0] = fmaf(a1, bb.x, acc[1][0]); acc[1][1] = fmaf(a1, bb.y, acc[1][1]);
      acc[1][2] = fmaf(a1, bb.z, acc[1][2]); acc[1][3] = fmaf(a1, bb.w, acc[1][3]);
      acc[2][0] = fmaf(a2, bb.x, acc[2][0]); acc[2][1] = fmaf(a2, bb.y, acc[2][1]);
      acc[2][2] = fmaf(a2, bb.z, acc[2][2]); acc[2][3] = fmaf(a2, bb.w, acc[2][3]);
      acc[3][0] = fmaf(a3, bb.x, acc[3][0]); acc[3][1] = fmaf(a3, bb.y, acc[3][1]);
      acc[3][2] = fmaf(a3, bb.z, acc[3][2]); acc[3][3] = fmaf(a3, bb.w, acc[3][3]);
    }

    if (which == 0) {
      u16* dst = Q + h * N * O;
#pragma unroll
      for (int i = 0; i < 4; i++) {
        u16x4 v4 = { f2bf(acc[i][0] * QSCALE), f2bf(acc[i][1] * QSCALE),
                     f2bf(acc[i][2] * QSCALE), f2bf(acc[i][3] * QSCALE) };
        *(u16x4*)&dst[(brow + r0 + i) * O + c0] = v4;
      }
    } else if (which == 1) {
      u16* dst = K + h * N * O;
#pragma unroll
      for (int i = 0; i < 4; i++) {
        u16x4 v4 = { f2bf(acc[i][0]), f2bf(acc[i][1]), f2bf(acc[i][2]), f2bf(acc[i][3]) };
        *(u16x4*)&dst[(brow + r0 + i) * O + c0] = v4;
      }
    } else {
      u16* dst = Vt + h * O * N;  // transposed store: Vt[o][n]
#pragma unroll
      for (int j = 0; j < 4; j++) {
        u16x4 v4 = { f2bf(acc[0][j]), f2bf(acc[1][j]), f2bf(acc[2][j]), f2bf(acc[3][j]) };
        *(u16x4*)&dst[(c0 + j) * N + brow + r0] = v4;
      }
    }
  } else {
    // ---- mask: row_mask[n] = any(x[n][f] != 0) ----
    int n = (b - 1792) * 256 + t;
    const float4* xr = (const float4*)(x + n * F);
    float s = 0.f;
#pragma unroll
    for (int i = 0; i < F / 4; i++) {
      float4 v = xr[i];
      s += fabsf(v.x) + fabsf(v.y) + fabsf(v.z) + fabsf(v.w);
    }
    rmask[n] = (s != 0.f) ? 1.f : 0.f;
  }
}

// ---------------------------------------------------------------------------
// Fused masked attention, staged-LDS, counted-vmcnt pipeline (T4/m201).
// grid (N/64, H, 2), block 512 = 8 waves = 4 row-groups x 2 column-halves.
// Per iter: issue bits(t+1)+STAGE(t+1) [8 VMEM ops], s_waitcnt vmcnt(8)
// (= oldest 8: bits-t + stage-t, issued a full iter ago -> ~free), barrier,
// compute tile t, barrier. Prefetch stays in flight across both barriers —
// no vmcnt(0) drain in the loop (the m97-ceiling stall).
// K,V staged via global_load_lds (double-buffered, XOR-swizzled, rule #21);
// LDS = kv 64KB + pst 16KB = exactly 80KB -> 2 blocks/CU.
// leaky = fmaxf(s, 0.2s); row-sums via ones-MFMA; Q pre-scaled (QSCALE) so
// P = 2^(leaky(s)). MFMA 16x16x32 bf16, C/D row=(l>>4)*4+r, col=l&15 (m89).
// ---------------------------------------------------------------------------
__global__ __launch_bounds__(512) void attn_kernel(
    const u64* __restrict__ bits, const u16* __restrict__ Qg,
    const u16* __restrict__ Kg, const u16* __restrict__ Vtg,
    float* __restrict__ Opart, float* __restrict__ Spart) {
  __shared__ __align__(16) char kv[2][4][8192];   // [buf][K0,K1,V0,V1][64x128B]
  __shared__ __align__(16) u16 pst[8][16][64];    // per-wave P staging, swizzled

  const int tid = threadIdx.x;
  const int w = tid >> 6, l = tid & 63;
  const int lm = l & 15, lg = l >> 4;
  const int rg = w >> 1, hc = w & 1;     // row-group 0..3, column-half 0..1
  const int h = blockIdx.y;
  const int z = blockIdx.z;              // column slice 0..1 (2048 cols each)
  const int R0 = blockIdx.x * 64;
  const int WR0 = R0 + rg * 16;          // this wave's 16 Q-rows
  const int CB0 = z * 2048;              // this block's column base

  const char* Kb = (const char*)(Kg + h * N * O);    // 128B per key-row
  const char* Vb = (const char*)(Vtg + h * O * N);   // 8KB per o-row
  const u64* bblk = bits + (size_t)WR0 * NW;

  // staging geometry: lane fills LDS slot (row=w*8+(l>>3), col=(l&7)*16);
  // source is the INVERSE-swizzled global column (involution).
  const int srow = w * 8 + (l >> 3);                   // 0..63
  const int scol = ((l & 7) * 16) ^ ((srow & 7) << 4); // swizzled 16B chunk

  // Q fragments (held in regs): A[m=lm][k=lg*8+j]
  const u16* Qh = Qg + h * N * O;
  bf16x8 qa0 = *(const bf16x8*)&Qh[(WR0 + lm) * O + lg * 8];
  bf16x8 qa1 = *(const bf16x8*)&Qh[(WR0 + lm) * O + 32 + lg * 8];

  // all-ones bf16 B-fragment for the row-sum MFMA
  bf16x8 ones;
#pragma unroll
  for (int i = 0; i < 8; i++) ones[i] = (short)0x3F80;

  // pst addressing (byte offsets into this wave's 2KB slot), swizzled
  char* pbase = (char*)&pst[w][0][0];
  const char* prd0 = pbase + lm * 128 + ((lg * 16) ^ ((lm & 7) << 4));
  const char* prd1 = pbase + lm * 128 + ((64 + lg * 16) ^ ((lm & 7) << 4));

  f32x4 oacc[4];
  f32x4 lacc = {0.f, 0.f, 0.f, 0.f};     // row-sum accumulator (ones-MFMA)
#pragma unroll
  for (int i = 0; i < 4; i++) oacc[i] = (f32x4){0.f, 0.f, 0.f, 0.f};
  const f32x4 zero4 = {0.f, 0.f, 0.f, 0.f};

  auto STAGE = [&](int b, int t) {
    __builtin_amdgcn_global_load_lds(
        (const u32*)(Kb + (size_t)(CB0 + 0 * 1024 + t * 64 + srow) * 128 + scol),
        (u32*)&kv[b][0][w * 1024], 16, 0, 0);
    __builtin_amdgcn_global_load_lds(
        (const u32*)(Kb + (size_t)(CB0 + 1 * 1024 + t * 64 + srow) * 128 + scol),
        (u32*)&kv[b][1][w * 1024], 16, 0, 0);
    __builtin_amdgcn_global_load_lds(
        (const u32*)(Vb + (size_t)srow * (N * 2) + (CB0 + 0 * 1024 + t * 64) * 2 + scol),
        (u32*)&kv[b][2][w * 1024], 16, 0, 0);
    __builtin_amdgcn_global_load_lds(
        (const u32*)(Vb + (size_t)srow * (N * 2) + (CB0 + 1 * 1024 + t * 64) * 2 + scol),
        (u32*)&kv[b][3][w * 1024], 16, 0, 0);
  };

  const int wb = (CB0 >> 6) + hc * NT;   // this wave's 64-col word base
  // ---- prologue: bits(0) + tile 0 (waited via iter-0's vmcnt(8)) ----
  u64 cur0 = bblk[(lg * 4 + 0) * NW + wb];
  u64 cur1 = bblk[(lg * 4 + 1) * NW + wb];
  u64 cur2 = bblk[(lg * 4 + 2) * NW + wb];
  u64 cur3 = bblk[(lg * 4 + 3) * NW + wb];
  STAGE(0, 0);

  int b = 0;
#pragma unroll 1
  for (int t = 0; t < NT; ++t) {
    // ---- issue next-tile prefetches (8 VMEM ops), counted wait on tile t ----
    u64 nx0 = 0, nx1 = 0, nx2 = 0, nx3 = 0;
    if (t + 1 < NT) {
      nx0 = bblk[(lg * 4 + 0) * NW + wb + t + 1];
      nx1 = bblk[(lg * 4 + 1) * NW + wb + t + 1];
      nx2 = bblk[(lg * 4 + 2) * NW + wb + t + 1];
      nx3 = bblk[(lg * 4 + 3) * NW + wb + t + 1];
      STAGE(b ^ 1, t + 1);
      asm volatile("s_waitcnt vmcnt(8)" ::: "memory");   // oldest 8 = bits-t + stage-t
    } else {
      asm volatile("s_waitcnt vmcnt(0)" ::: "memory");   // epilogue drain
    }
    __builtin_amdgcn_s_barrier();          // all waves: tile t fully in LDS
    __builtin_amdgcn_sched_barrier(0);     // no ds_read hoist above barrier

    // ---- S = Q K^T from staged K tile (swizzled reads) ----
    const char* Kt = &kv[b][hc][0];
    f32x4 sacc[4];
    __builtin_amdgcn_s_setprio(1);
#pragma unroll
    for (int tt = 0; tt < 4; tt++) {
      const int row = tt * 16 + lm;
      const int sw = (row & 7) << 4;
      bf16x8 kb0 = *(const bf16x8*)(Kt + row * 128 + ((lg * 16) ^ sw));
      bf16x8 kb1 = *(const bf16x8*)(Kt + row * 128 + ((lg * 16 + 64) ^ sw));
      f32x4 s0 = __builtin_amdgcn_mfma_f32_16x16x32_bf16(qa0, kb0, zero4, 0, 0, 0);
      sacc[tt] = __builtin_amdgcn_mfma_f32_16x16x32_bf16(qa1, kb1, s0, 0, 0, 0);
    }
    __builtin_amdgcn_s_setprio(0);

    // ---- P = adj ? 2^(max(s,0.2s)) : 0 ; stage bf16 P (swizzled) ----
#pragma unroll
    for (int tt = 0; tt < 4; tt++) {
#pragma unroll
      for (int r = 0; r < 4; r++) {
        u64 cr = (r == 0 ? cur0 : r == 1 ? cur1 : r == 2 ? cur2 : cur3);
        unsigned bit = (unsigned)(cr >> (tt * 16 + lm)) & 1u;
        float sv = sacc[tt][r];
        float lv = fmaxf(sv, 0.2f * sv);          // LeakyReLU, exact both signs
        float p = bit ? exp2_hw(lv) : 0.f;
        const int prow = lg * 4 + r;
        *(u16*)(pbase + prow * 128 +
                ((((tt * 16 + lm) * 2)) ^ ((prow & 7) << 4))) = f2bf(p);
      }
    }
    bf16x8 pa0 = *(const bf16x8*)prd0;
    bf16x8 pa1 = *(const bf16x8*)prd1;

    // ---- O += P V ; row-sums += P 1 (ones-MFMA) ----
    const char* Vt_ = &kv[b][2 + hc][0];
    __builtin_amdgcn_s_setprio(1);
#pragma unroll
    for (int ot = 0; ot < 4; ot++) {
      const int o = ot * 16 + lm;
      const int sw = (o & 7) << 4;
      bf16x8 vb0 = *(const bf16x8*)(Vt_ + o * 128 + ((lg * 16) ^ sw));
      bf16x8 vb1 = *(const bf16x8*)(Vt_ + o * 128 + ((lg * 16 + 64) ^ sw));
      oacc[ot] = __builtin_amdgcn_mfma_f32_16x16x32_bf16(pa0, vb0, oacc[ot], 0, 0, 0);
      oacc[ot] = __builtin_amdgcn_mfma_f32_16x16x32_bf16(pa1, vb1, oacc[ot], 0, 0, 0);
    }
    lacc = __builtin_amdgcn_mfma_f32_16x16x32_bf16(pa0, ones, lacc, 0, 0, 0);
    lacc = __builtin_amdgcn_mfma_f32_16x16x32_bf16(pa1, ones, lacc, 0, 0, 0);
    __builtin_amdgcn_s_setprio(0);

    __builtin_amdgcn_sched_barrier(0);     // keep compute above the barrier
    __builtin_amdgcn_s_barrier();          // compute done before next STAGE lands
    cur0 = nx0; cur1 = nx1; cur2 = nx2; cur3 = nx3;
    b ^= 1;
  }

  // ---- merge the 2 column-halves in LDS (Om2 aliases kv; barrier-safe).
  // Wave row-sums (lacc, replicated per col) parked raw in own pst slot. ----
  float (*Om2)[64][64] = (float (*)[64][64])&kv[0][0][0];  // 32KB
#pragma unroll
  for (int ot = 0; ot < 4; ot++)
#pragma unroll
    for (int r = 0; r < 4; r++)
      Om2[hc][rg * 16 + lg * 4 + r][ot * 16 + lm] = oacc[ot][r];
  if (lm == 0) {
    float* ps = (float*)pbase;
#pragma unroll
    for (int r = 0; r < 4; r++) ps[lg * 4 + r] = lacc[r];
  }
  __syncthreads();

  // ---- write partials: Opart[z][h][row][col], Spart[z][h][row] ----
  const int row = tid >> 3;          // 0..63
  const int c0 = (tid & 7) * 8;      // 0..56
  const int grow = R0 + row;
  float* op = &Opart[(((size_t)z * H + h) * N + grow) * O + c0];
#pragma unroll
  for (int j = 0; j < 8; j++)
    op[j] = Om2[0][row][c0 + j] + Om2[1][row][c0 + j];
  if ((tid & 7) == 0) {
    const int rg2 = row >> 4, ri = row & 15;
    float s0 = ((float*)&pst[rg2 * 2 + 0][0][0])[ri];
    float s1 = ((float*)&pst[rg2 * 2 + 1][0][0])[ri];
    Spart[((size_t)z * H + h) * N + grow] = s0 + s1;
  }
}

// ---------------------------------------------------------------------------
// Merge the 2 z-slices: out = relu((O0+O1)/(S0+S1)) * rowmask.
// ---------------------------------------------------------------------------
__global__ __launch_bounds__(256) void merge_kernel(
    const float* __restrict__ Opart, const float* __restrict__ Spart,
    const float* __restrict__ rowmask, float* __restrict__ out) {
  const int h = blockIdx.y;
  const int idx = blockIdx.x * 256 + threadIdx.x;
  const int row = idx >> 4, c0 = (idx & 15) * 4;
  float S = Spart[(size_t)h * N + row] + Spart[((size_t)H + h) * N + row];
  float inv = (S > 0.f) ? 1.f / S : 0.f;
  float rm = rowmask[row];
  const float4 o0 = *(const float4*)&Opart[((size_t)h * N + row) * O + c0];
  const float4 o1 = *(const float4*)&Opart[(((size_t)H + h) * N + row) * O + c0];
  float4 r;
  r.x = fmaxf((o0.x + o1.x) * inv, 0.f) * rm;
  r.y = fmaxf((o0.y + o1.y) * inv, 0.f) * rm;
  r.z = fmaxf((o0.z + o1.z) * inv, 0.f) * rm;
  r.w = fmaxf((o0.w + o1.w) * inv, 0.f) * rm;
  *(float4*)&out[(size_t)row * (H * O) + h * O + c0] = r;
}

extern "C" void kernel_launch(void* const* d_in, const int* in_sizes, int n_in,
                              void* d_out, int out_size, void* d_ws, size_t ws_size,
                              hipStream_t stream) {
  const float* x   = (const float*)d_in[0];  // h [1,4096,128]
  const float* adj = (const float*)d_in[1];  // a [1,4096,4096]
  const float* wv  = (const float*)d_in[2];  // kernel      -> V
  const float* wq  = (const float*)d_in[3];  // attn_kernel -> Q (f_self)
  const float* wk  = (const float*)d_in[4];  // attn_kernel2-> K (f_other)
  float* out = (float*)d_out;

  u16* Q  = (u16*)d_ws;                     // [4][4096][64] bf16  (2 MB)
  u16* K  = Q + H * N * O;                  // [4][4096][64] bf16  (2 MB)
  u16* Vt = K + H * N * O;                  // [4][64][4096] bf16  (2 MB)
  float* rmask = (float*)(Vt + H * N * O);  // [4096] f32 (16 KB)
  u64* bits = (u64*)(rmask + N);            // [4096][64] u64 (2 MB)
  float* Opart = (float*)(bits + (size_t)N * NW);  // [2][4][4096][64] f32 (8 MB)
  float* Spart = Opart + (size_t)2 * H * N * O;    // [2][4][4096] f32 (128 KB)

  prep_kernel<<<dim3(1808), 256, 0, stream>>>(x, adj, wv, wq, wk, Q, K, Vt, rmask, bits);
  attn_kernel<<<dim3(N / 64, H, 2), 512, 0, stream>>>(bits, Q, K, Vt, Opart, Spart);
  merge_kernel<<<dim3(N * O / 4 / 256, H), 256, 0, stream>>>(Opart, Spart, rmask, out);
}

// Round 14
// 69.053 us; speedup vs baseline: 1.1025x; 1.1025x over previous
//
#include <hip/hip_runtime.h>
#include <hip/hip_bf16.h>

typedef unsigned short u16;
typedef unsigned int u32;
typedef unsigned long long u64;
typedef __attribute__((ext_vector_type(8))) short bf16x8;
typedef __attribute__((ext_vector_type(4))) float f32x4;
typedef __attribute__((ext_vector_type(4))) u16 u16x4;

#define N 4096
#define F 128
#define H 4
#define O 64
#define NW (N / 64)   // 64-bit words per adjacency row
#define NT 16         // KV tiles per column-half per z-slice (1024/64)
// log2(e)/8: folds the /sqrt(64) and the exp->exp2 conversion into Q.
#define QSCALE 0.18033688011112043f

__device__ inline float exp2_hw(float x) {
#if __has_builtin(__builtin_amdgcn_exp2f)
  return __builtin_amdgcn_exp2f(x);      // v_exp_f32, hazards handled by compiler
#else
  return __expf(x * 0.6931471805599453f);
#endif
}

__device__ inline u16 f2bf(float f) {           // RNE convert
  union { __hip_bfloat16 b; u16 u; } v;
  v.b = __float2bfloat16(f);
  return v.u;
}

// ---------------------------------------------------------------------------
// Fused prep: [0,1024) pack | [1024,1792) proj (bf16 MFMA) | [1792,1808) mask.
// proj uses the SAME verified MFMA fragment mapping as attn:
// A-frag row=lm, B-frag col=lm, D row=lg*4+r / col=lm (m89).
// ---------------------------------------------------------------------------
__global__ __launch_bounds__(256) void prep_kernel(
    const float* __restrict__ x, const float* __restrict__ adj,
    const float* __restrict__ wv, const float* __restrict__ wq,
    const float* __restrict__ wk, u16* __restrict__ Q, u16* __restrict__ K,
    u16* __restrict__ Vt, float* __restrict__ rmask, u64* __restrict__ bits) {
  const int b = blockIdx.x;
  const int t = threadIdx.x;

  if (b < 1024) {
    // ---- pack: adjacency (0/1 fp32) -> bitmask ----
    const int w = t >> 6, l = t & 63;
    const int row = b * 4 + w;
    const float* ar = adj + (size_t)row * N;
    u64* br = bits + (size_t)row * NW;
#pragma unroll 4
    for (int j2 = 0; j2 < 16; j2++) {
      float4 v = *(const float4*)&ar[j2 * 256 + l * 4];
      unsigned nib = (unsigned)(v.x != 0.f) | ((unsigned)(v.y != 0.f) << 1) |
                     ((unsigned)(v.z != 0.f) << 2) | ((unsigned)(v.w != 0.f) << 3);
      u64 word = (u64)nib << ((l & 15) * 4);
      word |= __shfl_xor(word, 1);
      word |= __shfl_xor(word, 2);
      word |= __shfl_xor(word, 4);
      word |= __shfl_xor(word, 8);
      if ((l & 15) == 0) br[j2 * 4 + (l >> 4)] = word;
    }
  } else if (b < 1792) {
    // ---- proj: bf16 MFMA GEMM. xb = x-tile; wt[n][k] = W[k][n] (transposed).
    // Stride 136 u16 = 272B rows: 16B-aligned, odd 16B-granule -> rotated banks.
    __shared__ __align__(16) u16 xb[64][136];
    __shared__ __align__(16) u16 wt[64][136];
    const int pb = b - 1024;
    const int brow = (pb & 63) * 64;
    const int p = pb >> 6, h = p / 3, which = p % 3;
    const float* W = (which == 0 ? wq : which == 1 ? wk : wv) + h * F * O;

#pragma unroll
    for (int i = 0; i < 8; i++) {          // x tile 64x128 fp32 -> bf16
      int idx = t + i * 256, r = idx >> 5, c4 = idx & 31;
      float4 v = *(const float4*)&x[(brow + r) * F + c4 * 4];
      u16x4 o4 = { f2bf(v.x), f2bf(v.y), f2bf(v.z), f2bf(v.w) };
      *(u16x4*)&xb[r][c4 * 4] = o4;
    }
#pragma unroll
    for (int i = 0; i < 8; i++) {          // W 128x64 fp32 -> wt[n][k] bf16
      int idx = t + i * 256, k = idx >> 4, n4 = idx & 15;
      float4 v = *(const float4*)&W[k * O + n4 * 4];
      wt[n4 * 4 + 0][k] = f2bf(v.x);
      wt[n4 * 4 + 1][k] = f2bf(v.y);
      wt[n4 * 4 + 2][k] = f2bf(v.z);
      wt[n4 * 4 + 3][k] = f2bf(v.w);
    }
    __syncthreads();

    const int w = t >> 6, l = t & 63;
    const int lm = l & 15, lg = l >> 4;
    const f32x4 z4 = {0.f, 0.f, 0.f, 0.f};
    bf16x8 af[4];
#pragma unroll
    for (int kc = 0; kc < 4; kc++)         // A[m=lm][k=kc*32+lg*8+j]
      af[kc] = *(const bf16x8*)&xb[w * 16 + lm][kc * 32 + lg * 8];
    f32x4 acc[4];
#pragma unroll
    for (int ct = 0; ct < 4; ct++) {
      acc[ct] = z4;
#pragma unroll
      for (int kc = 0; kc < 4; kc++) {     // B[n=ct*16+lm][k] from wt
        bf16x8 bfr = *(const bf16x8*)&wt[ct * 16 + lm][kc * 32 + lg * 8];
        acc[ct] = __builtin_amdgcn_mfma_f32_16x16x32_bf16(af[kc], bfr, acc[ct], 0, 0, 0);
      }
    }

    const int orow = brow + w * 16 + lg * 4;   // D row = lg*4+r, col = ct*16+lm
    if (which == 0) {                          // Q: pre-scale by QSCALE
      u16* dst = Q + h * N * O;
#pragma unroll
      for (int ct = 0; ct < 4; ct++)
#pragma unroll
        for (int r = 0; r < 4; r++)
          dst[(orow + r) * O + ct * 16 + lm] = f2bf(acc[ct][r] * QSCALE);
    } else if (which == 1) {
      u16* dst = K + h * N * O;
#pragma unroll
      for (int ct = 0; ct < 4; ct++)
#pragma unroll
        for (int r = 0; r < 4; r++)
          dst[(orow + r) * O + ct * 16 + lm] = f2bf(acc[ct][r]);
    } else {
      u16* dst = Vt + h * O * N;               // Vt[o][n]: 4 consecutive n -> u16x4
#pragma unroll
      for (int ct = 0; ct < 4; ct++) {
        u16x4 v4 = { f2bf(acc[ct][0]), f2bf(acc[ct][1]),
                     f2bf(acc[ct][2]), f2bf(acc[ct][3]) };
        *(u16x4*)&dst[(size_t)(ct * 16 + lm) * N + orow] = v4;
      }
    }
  } else {
    // ---- mask: row_mask[n] = any(x[n][f] != 0) ----
    int n = (b - 1792) * 256 + t;
    const float4* xr = (const float4*)(x + n * F);
    float s = 0.f;
#pragma unroll
    for (int i = 0; i < F / 4; i++) {
      float4 v = xr[i];
      s += fabsf(v.x) + fabsf(v.y) + fabsf(v.z) + fabsf(v.w);
    }
    rmask[n] = (s != 0.f) ? 1.f : 0.f;
  }
}

// ---------------------------------------------------------------------------
// Fused masked attention, staged-LDS pipelined (R12-verified, 46.8us).
// grid (N/64, H, 2), block 512 = 8 waves = 4 row-groups x 2 column-halves.
// K AND V staged via global_load_lds (double-buffered, XOR-swizzled, #21);
// LDS = kv 64KB + pst 16KB = exactly 80KB -> 2 blocks/CU.
// leaky = fmaxf(s, 0.2s); row-sums via ones-MFMA; Q pre-scaled (QSCALE) so
// P = 2^(leaky(s)). MFMA 16x16x32 bf16, C/D row=(l>>4)*4+r, col=l&15 (m89).
// ---------------------------------------------------------------------------
__global__ __launch_bounds__(512) void attn_kernel(
    const u64* __restrict__ bits, const u16* __restrict__ Qg,
    const u16* __restrict__ Kg, const u16* __restrict__ Vtg,
    float* __restrict__ Opart, float* __restrict__ Spart) {
  __shared__ __align__(16) char kv[2][4][8192];   // [buf][K0,K1,V0,V1][64x128B]
  __shared__ __align__(16) u16 pst[8][16][64];    // per-wave P staging, swizzled

  const int tid = threadIdx.x;
  const int w = tid >> 6, l = tid & 63;
  const int lm = l & 15, lg = l >> 4;
  const int rg = w >> 1, hc = w & 1;     // row-group 0..3, column-half 0..1
  const int h = blockIdx.y;
  const int z = blockIdx.z;              // column slice 0..1 (2048 cols each)
  const int R0 = blockIdx.x * 64;
  const int WR0 = R0 + rg * 16;          // this wave's 16 Q-rows
  const int CB0 = z * 2048;              // this block's column base

  const char* Kb = (const char*)(Kg + h * N * O);    // 128B per key-row
  const char* Vb = (const char*)(Vtg + h * O * N);   // 8KB per o-row
  const u64* bblk = bits + (size_t)WR0 * NW;

  // staging geometry: lane fills LDS slot (row=w*8+(l>>3), col=(l&7)*16);
  // source is the INVERSE-swizzled global column (involution).
  const int srow = w * 8 + (l >> 3);                   // 0..63
  const int scol = ((l & 7) * 16) ^ ((srow & 7) << 4); // swizzled 16B chunk

  // Q fragments (held in regs): A[m=lm][k=lg*8+j]
  const u16* Qh = Qg + h * N * O;
  bf16x8 qa0 = *(const bf16x8*)&Qh[(WR0 + lm) * O + lg * 8];
  bf16x8 qa1 = *(const bf16x8*)&Qh[(WR0 + lm) * O + 32 + lg * 8];

  // all-ones bf16 B-fragment for the row-sum MFMA
  bf16x8 ones;
#pragma unroll
  for (int i = 0; i < 8; i++) ones[i] = (short)0x3F80;

  // pst addressing (byte offsets into this wave's 2KB slot), swizzled
  char* pbase = (char*)&pst[w][0][0];
  const char* prd0 = pbase + lm * 128 + ((lg * 16) ^ ((lm & 7) << 4));
  const char* prd1 = pbase + lm * 128 + ((64 + lg * 16) ^ ((lm & 7) << 4));

  f32x4 oacc[4];
  f32x4 lacc = {0.f, 0.f, 0.f, 0.f};     // row-sum accumulator (ones-MFMA)
#pragma unroll
  for (int i = 0; i < 4; i++) oacc[i] = (f32x4){0.f, 0.f, 0.f, 0.f};
  const f32x4 zero4 = {0.f, 0.f, 0.f, 0.f};

  auto STAGE = [&](int b, int t) {
    __builtin_amdgcn_global_load_lds(
        (const u32*)(Kb + (size_t)(CB0 + 0 * 1024 + t * 64 + srow) * 128 + scol),
        (u32*)&kv[b][0][w * 1024], 16, 0, 0);
    __builtin_amdgcn_global_load_lds(
        (const u32*)(Kb + (size_t)(CB0 + 1 * 1024 + t * 64 + srow) * 128 + scol),
        (u32*)&kv[b][1][w * 1024], 16, 0, 0);
    __builtin_amdgcn_global_load_lds(
        (const u32*)(Vb + (size_t)srow * (N * 2) + (CB0 + 0 * 1024 + t * 64) * 2 + scol),
        (u32*)&kv[b][2][w * 1024], 16, 0, 0);
    __builtin_amdgcn_global_load_lds(
        (const u32*)(Vb + (size_t)srow * (N * 2) + (CB0 + 1 * 1024 + t * 64) * 2 + scol),
        (u32*)&kv[b][3][w * 1024], 16, 0, 0);
  };

  STAGE(0, 0);
  __syncthreads();

  int b = 0;
#pragma unroll 1
  for (int t = 0; t < NT; ++t) {
    if (t + 1 < NT) STAGE(b ^ 1, t + 1);   // prefetch next tile (other buffer)

    const int widx = (CB0 >> 6) + hc * NT + t;   // 64-col word index

    // adjacency words (broadcast, L2-hot)
    u64 sh0 = bblk[(lg * 4 + 0) * NW + widx] >> lm;
    u64 sh1 = bblk[(lg * 4 + 1) * NW + widx] >> lm;
    u64 sh2 = bblk[(lg * 4 + 2) * NW + widx] >> lm;
    u64 sh3 = bblk[(lg * 4 + 3) * NW + widx] >> lm;

    // ---- S = Q K^T from staged K tile (swizzled reads) ----
    const char* Kt = &kv[b][hc][0];
    f32x4 sacc[4];
    __builtin_amdgcn_s_setprio(1);
#pragma unroll
    for (int tt = 0; tt < 4; tt++) {
      const int row = tt * 16 + lm;
      const int sw = (row & 7) << 4;
      bf16x8 kb0 = *(const bf16x8*)(Kt + row * 128 + ((lg * 16) ^ sw));
      bf16x8 kb1 = *(const bf16x8*)(Kt + row * 128 + ((lg * 16 + 64) ^ sw));
      f32x4 s0 = __builtin_amdgcn_mfma_f32_16x16x32_bf16(qa0, kb0, zero4, 0, 0, 0);
      sacc[tt] = __builtin_amdgcn_mfma_f32_16x16x32_bf16(qa1, kb1, s0, 0, 0, 0);
    }
    __builtin_amdgcn_s_setprio(0);

    // ---- P = adj ? 2^(max(s,0.2s)) : 0 ; stage bf16 P (swizzled) ----
#pragma unroll
    for (int tt = 0; tt < 4; tt++) {
#pragma unroll
      for (int r = 0; r < 4; r++) {
        u64 sh = (r == 0 ? sh0 : r == 1 ? sh1 : r == 2 ? sh2 : sh3);
        unsigned bit = (unsigned)(sh >> (tt * 16)) & 1u;
        float sv = sacc[tt][r];
        float lv = fmaxf(sv, 0.2f * sv);          // LeakyReLU, exact both signs
        float p = bit ? exp2_hw(lv) : 0.f;
        const int prow = lg * 4 + r;
        *(u16*)(pbase + prow * 128 +
                ((((tt * 16 + lm) * 2)) ^ ((prow & 7) << 4))) = f2bf(p);
      }
    }
    bf16x8 pa0 = *(const bf16x8*)prd0;
    bf16x8 pa1 = *(const bf16x8*)prd1;

    // ---- O += P V ; row-sums += P 1 (ones-MFMA) ----
    const char* Vt_ = &kv[b][2 + hc][0];
    __builtin_amdgcn_s_setprio(1);
#pragma unroll
    for (int ot = 0; ot < 4; ot++) {
      const int o = ot * 16 + lm;
      const int sw = (o & 7) << 4;
      bf16x8 vb0 = *(const bf16x8*)(Vt_ + o * 128 + ((lg * 16) ^ sw));
      bf16x8 vb1 = *(const bf16x8*)(Vt_ + o * 128 + ((lg * 16 + 64) ^ sw));
      oacc[ot] = __builtin_amdgcn_mfma_f32_16x16x32_bf16(pa0, vb0, oacc[ot], 0, 0, 0);
      oacc[ot] = __builtin_amdgcn_mfma_f32_16x16x32_bf16(pa1, vb1, oacc[ot], 0, 0, 0);
    }
    lacc = __builtin_amdgcn_mfma_f32_16x16x32_bf16(pa0, ones, lacc, 0, 0, 0);
    lacc = __builtin_amdgcn_mfma_f32_16x16x32_bf16(pa1, ones, lacc, 0, 0, 0);
    __builtin_amdgcn_s_setprio(0);

    __syncthreads();   // drains prefetch + protects buffer flip
    b ^= 1;
  }

  // ---- merge the 2 column-halves in LDS (Om2 aliases kv; barrier-safe).
  // Wave row-sums (lacc, replicated per col) parked raw in own pst slot. ----
  float (*Om2)[64][64] = (float (*)[64][64])&kv[0][0][0];  // 32KB
#pragma unroll
  for (int ot = 0; ot < 4; ot++)
#pragma unroll
    for (int r = 0; r < 4; r++)
      Om2[hc][rg * 16 + lg * 4 + r][ot * 16 + lm] = oacc[ot][r];
  if (lm == 0) {
    float* ps = (float*)pbase;
#pragma unroll
    for (int r = 0; r < 4; r++) ps[lg * 4 + r] = lacc[r];
  }
  __syncthreads();

  // ---- write partials: Opart[z][h][row][col], Spart[z][h][row] ----
  const int row = tid >> 3;          // 0..63
  const int c0 = (tid & 7) * 8;      // 0..56
  const int grow = R0 + row;
  float* op = &Opart[(((size_t)z * H + h) * N + grow) * O + c0];
#pragma unroll
  for (int j = 0; j < 8; j++)
    op[j] = Om2[0][row][c0 + j] + Om2[1][row][c0 + j];
  if ((tid & 7) == 0) {
    const int rg2 = row >> 4, ri = row & 15;
    float s0 = ((float*)&pst[rg2 * 2 + 0][0][0])[ri];
    float s1 = ((float*)&pst[rg2 * 2 + 1][0][0])[ri];
    Spart[((size_t)z * H + h) * N + grow] = s0 + s1;
  }
}

// ---------------------------------------------------------------------------
// Merge the 2 z-slices: out = relu((O0+O1)/(S0+S1)) * rowmask.
// ---------------------------------------------------------------------------
__global__ __launch_bounds__(256) void merge_kernel(
    const float* __restrict__ Opart, const float* __restrict__ Spart,
    const float* __restrict__ rowmask, float* __restrict__ out) {
  const int h = blockIdx.y;
  const int idx = blockIdx.x * 256 + threadIdx.x;
  const int row = idx >> 4, c0 = (idx & 15) * 4;
  float S = Spart[(size_t)h * N + row] + Spart[((size_t)H + h) * N + row];
  float inv = (S > 0.f) ? 1.f / S : 0.f;
  float rm = rowmask[row];
  const float4 o0 = *(const float4*)&Opart[((size_t)h * N + row) * O + c0];
  const float4 o1 = *(const float4*)&Opart[(((size_t)H + h) * N + row) * O + c0];
  float4 r;
  r.x = fmaxf((o0.x + o1.x) * inv, 0.f) * rm;
  r.y = fmaxf((o0.y + o1.y) * inv, 0.f) * rm;
  r.z = fmaxf((o0.z + o1.z) * inv, 0.f) * rm;
  r.w = fmaxf((o0.w + o1.w) * inv, 0.f) * rm;
  *(float4*)&out[(size_t)row * (H * O) + h * O + c0] = r;
}

extern "C" void kernel_launch(void* const* d_in, const int* in_sizes, int n_in,
                              void* d_out, int out_size, void* d_ws, size_t ws_size,
                              hipStream_t stream) {
  const float* x   = (const float*)d_in[0];  // h [1,4096,128]
  const float* adj = (const float*)d_in[1];  // a [1,4096,4096]
  const float* wv  = (const float*)d_in[2];  // kernel      -> V
  const float* wq  = (const float*)d_in[3];  // attn_kernel -> Q (f_self)
  const float* wk  = (const float*)d_in[4];  // attn_kernel2-> K (f_other)
  float* out = (float*)d_out;

  u16* Q  = (u16*)d_ws;                     // [4][4096][64] bf16  (2 MB)
  u16* K  = Q + H * N * O;                  // [4][4096][64] bf16  (2 MB)
  u16* Vt = K + H * N * O;                  // [4][64][4096] bf16  (2 MB)
  float* rmask = (float*)(Vt + H * N * O);  // [4096] f32 (16 KB)
  u64* bits = (u64*)(rmask + N);            // [4096][64] u64 (2 MB)
  float* Opart = (float*)(bits + (size_t)N * NW);  // [2][4][4096][64] f32 (8 MB)
  float* Spart = Opart + (size_t)2 * H * N * O;    // [2][4][4096] f32 (128 KB)

  prep_kernel<<<dim3(1808), 256, 0, stream>>>(x, adj, wv, wq, wk, Q, K, Vt, rmask, bits);
  attn_kernel<<<dim3(N / 64, H, 2), 512, 0, stream>>>(bits, Q, K, Vt, Opart, Spart);
  merge_kernel<<<dim3(N * O / 4 / 256, H), 256, 0, stream>>>(Opart, Spart, rmask, out);
}

// Round 16
// 67.438 us; speedup vs baseline: 1.1289x; 1.0240x over previous
//
#include <hip/hip_runtime.h>
#include <hip/hip_bf16.h>

typedef unsigned short u16;
typedef unsigned int u32;
typedef unsigned long long u64;
typedef __attribute__((ext_vector_type(8))) short bf16x8;
typedef __attribute__((ext_vector_type(4))) float f32x4;
typedef __attribute__((ext_vector_type(4))) u16 u16x4;

#define N 4096
#define F 128
#define H 4
#define O 64
#define NW (N / 64)   // 64-bit words per adjacency row
#define NT 16         // KV tiles per column-half per z-slice (1024/64)
// log2(e)/8: folds the /sqrt(64) and the exp->exp2 conversion into Q.
#define QSCALE 0.18033688011112043f

__device__ inline float exp2_hw(float x) {
#if __has_builtin(__builtin_amdgcn_exp2f)
  return __builtin_amdgcn_exp2f(x);      // v_exp_f32, hazards handled by compiler
#else
  return __expf(x * 0.6931471805599453f);
#endif
}

__device__ inline u16 f2bf(float f) {           // RNE convert
  union { __hip_bfloat16 b; u16 u; } v;
  v.b = __float2bfloat16(f);
  return v.u;
}

// ---------------------------------------------------------------------------
// Fused prep: [0,1024) pack | [1024,1792) proj (bf16 MFMA) | [1792,1808) mask.
// (verbatim R14 — verified)
// ---------------------------------------------------------------------------
__global__ __launch_bounds__(256) void prep_kernel(
    const float* __restrict__ x, const float* __restrict__ adj,
    const float* __restrict__ wv, const float* __restrict__ wq,
    const float* __restrict__ wk, u16* __restrict__ Q, u16* __restrict__ K,
    u16* __restrict__ Vt, float* __restrict__ rmask, u64* __restrict__ bits) {
  const int b = blockIdx.x;
  const int t = threadIdx.x;

  if (b < 1024) {
    // ---- pack: adjacency (0/1 fp32) -> bitmask ----
    const int w = t >> 6, l = t & 63;
    const int row = b * 4 + w;
    const float* ar = adj + (size_t)row * N;
    u64* br = bits + (size_t)row * NW;
#pragma unroll 4
    for (int j2 = 0; j2 < 16; j2++) {
      float4 v = *(const float4*)&ar[j2 * 256 + l * 4];
      unsigned nib = (unsigned)(v.x != 0.f) | ((unsigned)(v.y != 0.f) << 1) |
                     ((unsigned)(v.z != 0.f) << 2) | ((unsigned)(v.w != 0.f) << 3);
      u64 word = (u64)nib << ((l & 15) * 4);
      word |= __shfl_xor(word, 1);
      word |= __shfl_xor(word, 2);
      word |= __shfl_xor(word, 4);
      word |= __shfl_xor(word, 8);
      if ((l & 15) == 0) br[j2 * 4 + (l >> 4)] = word;
    }
  } else if (b < 1792) {
    // ---- proj: bf16 MFMA GEMM ----
    __shared__ __align__(16) u16 xb[64][136];
    __shared__ __align__(16) u16 wt[64][136];
    const int pb = b - 1024;
    const int brow = (pb & 63) * 64;
    const int p = pb >> 6, h = p / 3, which = p % 3;
    const float* W = (which == 0 ? wq : which == 1 ? wk : wv) + h * F * O;

#pragma unroll
    for (int i = 0; i < 8; i++) {          // x tile 64x128 fp32 -> bf16
      int idx = t + i * 256, r = idx >> 5, c4 = idx & 31;
      float4 v = *(const float4*)&x[(brow + r) * F + c4 * 4];
      u16x4 o4 = { f2bf(v.x), f2bf(v.y), f2bf(v.z), f2bf(v.w) };
      *(u16x4*)&xb[r][c4 * 4] = o4;
    }
#pragma unroll
    for (int i = 0; i < 8; i++) {          // W 128x64 fp32 -> wt[n][k] bf16
      int idx = t + i * 256, k = idx >> 4, n4 = idx & 15;
      float4 v = *(const float4*)&W[k * O + n4 * 4];
      wt[n4 * 4 + 0][k] = f2bf(v.x);
      wt[n4 * 4 + 1][k] = f2bf(v.y);
      wt[n4 * 4 + 2][k] = f2bf(v.z);
      wt[n4 * 4 + 3][k] = f2bf(v.w);
    }
    __syncthreads();

    const int w = t >> 6, l = t & 63;
    const int lm = l & 15, lg = l >> 4;
    const f32x4 z4 = {0.f, 0.f, 0.f, 0.f};
    bf16x8 af[4];
#pragma unroll
    for (int kc = 0; kc < 4; kc++)
      af[kc] = *(const bf16x8*)&xb[w * 16 + lm][kc * 32 + lg * 8];
    f32x4 acc[4];
#pragma unroll
    for (int ct = 0; ct < 4; ct++) {
      acc[ct] = z4;
#pragma unroll
      for (int kc = 0; kc < 4; kc++) {
        bf16x8 bfr = *(const bf16x8*)&wt[ct * 16 + lm][kc * 32 + lg * 8];
        acc[ct] = __builtin_amdgcn_mfma_f32_16x16x32_bf16(af[kc], bfr, acc[ct], 0, 0, 0);
      }
    }

    const int orow = brow + w * 16 + lg * 4;
    if (which == 0) {
      u16* dst = Q + h * N * O;
#pragma unroll
      for (int ct = 0; ct < 4; ct++)
#pragma unroll
        for (int r = 0; r < 4; r++)
          dst[(orow + r) * O + ct * 16 + lm] = f2bf(acc[ct][r] * QSCALE);
    } else if (which == 1) {
      u16* dst = K + h * N * O;
#pragma unroll
      for (int ct = 0; ct < 4; ct++)
#pragma unroll
        for (int r = 0; r < 4; r++)
          dst[(orow + r) * O + ct * 16 + lm] = f2bf(acc[ct][r]);
    } else {
      u16* dst = Vt + h * O * N;
#pragma unroll
      for (int ct = 0; ct < 4; ct++) {
        u16x4 v4 = { f2bf(acc[ct][0]), f2bf(acc[ct][1]),
                     f2bf(acc[ct][2]), f2bf(acc[ct][3]) };
        *(u16x4*)&dst[(size_t)(ct * 16 + lm) * N + orow] = v4;
      }
    }
  } else {
    // ---- mask ----
    int n = (b - 1792) * 256 + t;
    const float4* xr = (const float4*)(x + n * F);
    float s = 0.f;
#pragma unroll
    for (int i = 0; i < F / 4; i++) {
      float4 v = xr[i];
      s += fabsf(v.x) + fabsf(v.y) + fabsf(v.z) + fabsf(v.w);
    }
    rmask[n] = (s != 0.f) ? 1.f : 0.f;
  }
}

// ---------------------------------------------------------------------------
// Fused masked attention — SWAPPED QK^T (S^T = mfma(K,Q)) with sigma-permuted
// key order so P is ENTIRELY lane-local for PV (zero LDS round-trip):
//   sigma(tt,i) = 32(tt>>1) + 8(i>>2) + 4(tt&1) + (i&3)
//   lane (lm,lg) holds P[qrow=lm][keys 8lg..8lg+7 and 32+8lg..32+8lg+7]
//   = exactly the PV B-frag (col=lm, k=lg*8+j). Verified algebraically.
// grid (N/64, H, 2), block 512 = 8 waves = 4 row-groups x 2 column-halves.
// K,V staged via global_load_lds (double-buffered). Swizzle (rule #21):
//   sw_idx(row) = (row&3)|(((row>>3)&1)<<2)  (<=2-way for sigma'd K rows,
//   V rows, and staging). bits: 1 u64/lane/iter (q-row = lm).
// leaky = fmaxf(s,0.2s); row-sums via ones-MFMA (A=ones, B=P^T -> colsums).
// PV: O^T = mfma(V-frag, P-frag): D row=o (lg*4+r), col=qrow (lm).
// LDS = kv 64KB + Ss2 0.5KB -> 2 blocks/CU.
// ---------------------------------------------------------------------------
__global__ __launch_bounds__(512, 4) void attn_kernel(
    const u64* __restrict__ bits, const u16* __restrict__ Qg,
    const u16* __restrict__ Kg, const u16* __restrict__ Vtg,
    float* __restrict__ Opart, float* __restrict__ Spart) {
  __shared__ __align__(16) char kv[2][4][8192];   // [buf][K0,K1,V0,V1][64x128B]
  __shared__ float Ss2[8][16];                    // per-wave row-sums

  const int tid = threadIdx.x;
  const int w = tid >> 6, l = tid & 63;
  const int lm = l & 15, lg = l >> 4;
  const int rg = w >> 1, hc = w & 1;     // row-group 0..3, column-half 0..1
  const int h = blockIdx.y;
  const int z = blockIdx.z;              // column slice 0..1 (2048 cols each)
  const int R0 = blockIdx.x * 64;
  const int WR0 = R0 + rg * 16;          // this wave's 16 Q-rows
  const int CB0 = z * 2048;              // this block's column base

  const char* Kb = (const char*)(Kg + h * N * O);    // 128B per key-row
  const char* Vb = (const char*)(Vtg + h * O * N);   // 8KB per o-row
  const u64* bblk = bits + (size_t)WR0 * NW;

  // staging: lane fills LDS slot (row=w*8+(l>>3), col=(l&7)*16) linearly;
  // global source column inverse-swizzled with sw_idx(row).
  const int srow = w * 8 + (l >> 3);
  const int ssw = (((srow & 3) | (((srow >> 3) & 1) << 2)) << 4);
  const int scol = ((l & 7) * 16) ^ ssw;

  // K A-frag: rows sigma(tt,lm) = krow_base + {0,4,32,36}; sw_idx == lm&7.
  const int krow_base = (lm & 3) + 8 * (lm >> 2);
  const int ksw = (lm & 7) << 4;
  // V A-frag rows o=ot*16+lm: sw_idx = (lm&3)|(((lm>>3)&1)<<2).
  const int vsw = (((lm & 3) | (((lm >> 3) & 1) << 2)) << 4);

  // Q fragments (B-operand: col=lm=qrow, k=lg*8+j) — same layout as before.
  const u16* Qh = Qg + h * N * O;
  bf16x8 qa0 = *(const bf16x8*)&Qh[(WR0 + lm) * O + lg * 8];
  bf16x8 qa1 = *(const bf16x8*)&Qh[(WR0 + lm) * O + 32 + lg * 8];

  bf16x8 ones;
#pragma unroll
  for (int i = 0; i < 8; i++) ones[i] = (short)0x3F80;

  f32x4 oacc[4];
  f32x4 lacc = {0.f, 0.f, 0.f, 0.f};
#pragma unroll
  for (int i = 0; i < 4; i++) oacc[i] = (f32x4){0.f, 0.f, 0.f, 0.f};
  const f32x4 zero4 = {0.f, 0.f, 0.f, 0.f};

  auto STAGE = [&](int b, int t) {
    __builtin_amdgcn_global_load_lds(
        (const u32*)(Kb + (size_t)(CB0 + 0 * 1024 + t * 64 + srow) * 128 + scol),
        (u32*)&kv[b][0][w * 1024], 16, 0, 0);
    __builtin_amdgcn_global_load_lds(
        (const u32*)(Kb + (size_t)(CB0 + 1 * 1024 + t * 64 + srow) * 128 + scol),
        (u32*)&kv[b][1][w * 1024], 16, 0, 0);
    __builtin_amdgcn_global_load_lds(
        (const u32*)(Vb + (size_t)srow * (N * 2) + (CB0 + 0 * 1024 + t * 64) * 2 + scol),
        (u32*)&kv[b][2][w * 1024], 16, 0, 0);
    __builtin_amdgcn_global_load_lds(
        (const u32*)(Vb + (size_t)srow * (N * 2) + (CB0 + 1 * 1024 + t * 64) * 2 + scol),
        (u32*)&kv[b][3][w * 1024], 16, 0, 0);
  };

  STAGE(0, 0);
  __syncthreads();

  int b = 0;
#pragma unroll 1
  for (int t = 0; t < NT; ++t) {
    if (t + 1 < NT) STAGE(b ^ 1, t + 1);   // prefetch next tile (other buffer)

    const int widx = (CB0 >> 6) + hc * NT + t;

    // bits: ONE word per lane — q-row lm's 64 keys for this tile
    u64 word = bblk[lm * NW + widx];
    u64 w2 = word >> (8 * lg);             // lane's key base 8*lg

    // ---- S^T = mfma(K, Q): D row=key sigma(tt,lg*4+r), col=qrow=lm ----
    const char* Kt = &kv[b][hc][0];
    f32x4 sacc[4];
    __builtin_amdgcn_s_setprio(1);
#pragma unroll
    for (int tt = 0; tt < 4; tt++) {
      const int row = krow_base + 4 * (tt & 1) + 32 * (tt >> 1);
      bf16x8 kb0 = *(const bf16x8*)(Kt + row * 128 + ((lg * 16) ^ ksw));
      bf16x8 kb1 = *(const bf16x8*)(Kt + row * 128 + ((lg * 16 + 64) ^ ksw));
      f32x4 s0 = __builtin_amdgcn_mfma_f32_16x16x32_bf16(kb0, qa0, zero4, 0, 0, 0);
      sacc[tt] = __builtin_amdgcn_mfma_f32_16x16x32_bf16(kb1, qa1, s0, 0, 0, 0);
    }
    __builtin_amdgcn_s_setprio(0);

    // ---- P = adj ? 2^(max(s,0.2s)) : 0 — entirely in registers.
    // sacc[tt][r] = S[qrow=lm][key = 8lg + 4(tt&1) + 32(tt>>1) + r] ----
    float pv[4][4];
#pragma unroll
    for (int tt = 0; tt < 4; tt++) {
#pragma unroll
      for (int r = 0; r < 4; r++) {
        unsigned bit = (unsigned)(w2 >> (4 * (tt & 1) + 32 * (tt >> 1) + r)) & 1u;
        float sv = sacc[tt][r];
        float lv = fmaxf(sv, 0.2f * sv);
        pv[tt][r] = bit ? exp2_hw(lv) : 0.f;
      }
    }
    // PV B-frags: keys 0..31 from pv[0],pv[1]; keys 32..63 from pv[2],pv[3]
    bf16x8 pa0, pa1;
#pragma unroll
    for (int r = 0; r < 4; r++) {
      pa0[r]     = (short)f2bf(pv[0][r]);
      pa0[4 + r] = (short)f2bf(pv[1][r]);
      pa1[r]     = (short)f2bf(pv[2][r]);
      pa1[4 + r] = (short)f2bf(pv[3][r]);
    }

    // ---- O^T += mfma(V, P); row-sums via mfma(ones, P) ----
    const char* Vt_ = &kv[b][2 + hc][0];
    __builtin_amdgcn_s_setprio(1);
#pragma unroll
    for (int ot = 0; ot < 4; ot++) {
      const int o = ot * 16 + lm;
      bf16x8 vb0 = *(const bf16x8*)(Vt_ + o * 128 + ((lg * 16) ^ vsw));
      bf16x8 vb1 = *(const bf16x8*)(Vt_ + o * 128 + ((lg * 16 + 64) ^ vsw));
      oacc[ot] = __builtin_amdgcn_mfma_f32_16x16x32_bf16(vb0, pa0, oacc[ot], 0, 0, 0);
      oacc[ot] = __builtin_amdgcn_mfma_f32_16x16x32_bf16(vb1, pa1, oacc[ot], 0, 0, 0);
    }
    lacc = __builtin_amdgcn_mfma_f32_16x16x32_bf16(ones, pa0, lacc, 0, 0, 0);
    lacc = __builtin_amdgcn_mfma_f32_16x16x32_bf16(ones, pa1, lacc, 0, 0, 0);
    __builtin_amdgcn_s_setprio(0);

    __syncthreads();   // drains prefetch + protects buffer flip
    b ^= 1;
  }

  // ---- merge halves in LDS. O^T layout: oacc[ot][r] = O[qrow=lm][ot*16+lg*4+r]
  // Om2 stride 68 (pad) -> 2-way banks on the f32x4 writes. 34.8KB < 64KB kv.
  float (*Om2)[64][68] = (float (*)[64][68])&kv[0][0][0];
#pragma unroll
  for (int ot = 0; ot < 4; ot++)
    *(f32x4*)&Om2[hc][rg * 16 + lm][ot * 16 + lg * 4] = oacc[ot];
  if (lg == 0) Ss2[w][lm] = lacc[0];   // colsum for qrow=lm (replicated per r)
  __syncthreads();

  // ---- write partials: Opart[z][h][row][col], Spart[z][h][row] ----
  const int row = tid >> 3;          // 0..63
  const int c0 = (tid & 7) * 8;      // 0..56
  const int grow = R0 + row;
  float* op = &Opart[(((size_t)z * H + h) * N + grow) * O + c0];
#pragma unroll
  for (int j = 0; j < 8; j++)
    op[j] = Om2[0][row][c0 + j] + Om2[1][row][c0 + j];
  if ((tid & 7) == 0) {
    const int rg2 = row >> 4, ri = row & 15;
    Spart[((size_t)z * H + h) * N + grow] = Ss2[rg2 * 2 + 0][ri] + Ss2[rg2 * 2 + 1][ri];
  }
}

// ---------------------------------------------------------------------------
// Merge the 2 z-slices: out = relu((O0+O1)/(S0+S1)) * rowmask. (verbatim R14)
// ---------------------------------------------------------------------------
__global__ __launch_bounds__(256) void merge_kernel(
    const float* __restrict__ Opart, const float* __restrict__ Spart,
    const float* __restrict__ rowmask, float* __restrict__ out) {
  const int h = blockIdx.y;
  const int idx = blockIdx.x * 256 + threadIdx.x;
  const int row = idx >> 4, c0 = (idx & 15) * 4;
  float S = Spart[(size_t)h * N + row] + Spart[((size_t)H + h) * N + row];
  float inv = (S > 0.f) ? 1.f / S : 0.f;
  float rm = rowmask[row];
  const float4 o0 = *(const float4*)&Opart[((size_t)h * N + row) * O + c0];
  const float4 o1 = *(const float4*)&Opart[(((size_t)H + h) * N + row) * O + c0];
  float4 r;
  r.x = fmaxf((o0.x + o1.x) * inv, 0.f) * rm;
  r.y = fmaxf((o0.y + o1.y) * inv, 0.f) * rm;
  r.z = fmaxf((o0.z + o1.z) * inv, 0.f) * rm;
  r.w = fmaxf((o0.w + o1.w) * inv, 0.f) * rm;
  *(float4*)&out[(size_t)row * (H * O) + h * O + c0] = r;
}

extern "C" void kernel_launch(void* const* d_in, const int* in_sizes, int n_in,
                              void* d_out, int out_size, void* d_ws, size_t ws_size,
                              hipStream_t stream) {
  const float* x   = (const float*)d_in[0];  // h [1,4096,128]
  const float* adj = (const float*)d_in[1];  // a [1,4096,4096]
  const float* wv  = (const float*)d_in[2];  // kernel      -> V
  const float* wq  = (const float*)d_in[3];  // attn_kernel -> Q (f_self)
  const float* wk  = (const float*)d_in[4];  // attn_kernel2-> K (f_other)
  float* out = (float*)d_out;

  u16* Q  = (u16*)d_ws;                     // [4][4096][64] bf16  (2 MB)
  u16* K  = Q + H * N * O;                  // [4][4096][64] bf16  (2 MB)
  u16* Vt = K + H * N * O;                  // [4][64][4096] bf16  (2 MB)
  float* rmask = (float*)(Vt + H * N * O);  // [4096] f32 (16 KB)
  u64* bits = (u64*)(rmask + N);            // [4096][64] u64 (2 MB)
  float* Opart = (float*)(bits + (size_t)N * NW);  // [2][4][4096][64] f32 (8 MB)
  float* Spart = Opart + (size_t)2 * H * N * O;    // [2][4][4096] f32 (128 KB)

  prep_kernel<<<dim3(1808), 256, 0, stream>>>(x, adj, wv, wq, wk, Q, K, Vt, rmask, bits);
  attn_kernel<<<dim3(N / 64, H, 2), 512, 0, stream>>>(bits, Q, K, Vt, Opart, Spart);
  merge_kernel<<<dim3(N * O / 4 / 256, H), 256, 0, stream>>>(Opart, Spart, rmask, out);
}

// Round 17
// 66.848 us; speedup vs baseline: 1.1389x; 1.0088x over previous
//
#include <hip/hip_runtime.h>
#include <hip/hip_bf16.h>

typedef unsigned short u16;
typedef unsigned int u32;
typedef unsigned long long u64;
typedef __attribute__((ext_vector_type(8))) short bf16x8;
typedef __attribute__((ext_vector_type(4))) float f32x4;
typedef __attribute__((ext_vector_type(4))) u16 u16x4;

#define N 4096
#define F 128
#define H 4
#define O 64
#define NW (N / 64)   // 64-bit words per adjacency row
#define NT 8          // KV tiles per column-half per z-slice (512/64)
#define NZ 4          // key-range slices (1024 keys each)
// log2(e)/8: folds the /sqrt(64) and the exp->exp2 conversion into Q.
#define QSCALE 0.18033688011112043f

__device__ inline float exp2_hw(float x) {
#if __has_builtin(__builtin_amdgcn_exp2f)
  return __builtin_amdgcn_exp2f(x);      // v_exp_f32, hazards handled by compiler
#else
  return __expf(x * 0.6931471805599453f);
#endif
}

__device__ inline u16 f2bf(float f) {           // RNE convert
  union { __hip_bfloat16 b; u16 u; } v;
  v.b = __float2bfloat16(f);
  return v.u;
}

__device__ inline float bf2f(u16 u) {
  union { float f; u32 i; } v; v.i = ((u32)u) << 16; return v.f;
}

// ---------------------------------------------------------------------------
// Fused prep: [0,1024) pack | [1024,1792) proj (bf16 MFMA) | [1792,1808) mask.
// (verbatim R14 — verified)
// ---------------------------------------------------------------------------
__global__ __launch_bounds__(256) void prep_kernel(
    const float* __restrict__ x, const float* __restrict__ adj,
    const float* __restrict__ wv, const float* __restrict__ wq,
    const float* __restrict__ wk, u16* __restrict__ Q, u16* __restrict__ K,
    u16* __restrict__ Vt, float* __restrict__ rmask, u64* __restrict__ bits) {
  const int b = blockIdx.x;
  const int t = threadIdx.x;

  if (b < 1024) {
    // ---- pack: adjacency (0/1 fp32) -> bitmask ----
    const int w = t >> 6, l = t & 63;
    const int row = b * 4 + w;
    const float* ar = adj + (size_t)row * N;
    u64* br = bits + (size_t)row * NW;
#pragma unroll 4
    for (int j2 = 0; j2 < 16; j2++) {
      float4 v = *(const float4*)&ar[j2 * 256 + l * 4];
      unsigned nib = (unsigned)(v.x != 0.f) | ((unsigned)(v.y != 0.f) << 1) |
                     ((unsigned)(v.z != 0.f) << 2) | ((unsigned)(v.w != 0.f) << 3);
      u64 word = (u64)nib << ((l & 15) * 4);
      word |= __shfl_xor(word, 1);
      word |= __shfl_xor(word, 2);
      word |= __shfl_xor(word, 4);
      word |= __shfl_xor(word, 8);
      if ((l & 15) == 0) br[j2 * 4 + (l >> 4)] = word;
    }
  } else if (b < 1792) {
    // ---- proj: bf16 MFMA GEMM ----
    __shared__ __align__(16) u16 xb[64][136];
    __shared__ __align__(16) u16 wt[64][136];
    const int pb = b - 1024;
    const int brow = (pb & 63) * 64;
    const int p = pb >> 6, h = p / 3, which = p % 3;
    const float* W = (which == 0 ? wq : which == 1 ? wk : wv) + h * F * O;

#pragma unroll
    for (int i = 0; i < 8; i++) {          // x tile 64x128 fp32 -> bf16
      int idx = t + i * 256, r = idx >> 5, c4 = idx & 31;
      float4 v = *(const float4*)&x[(brow + r) * F + c4 * 4];
      u16x4 o4 = { f2bf(v.x), f2bf(v.y), f2bf(v.z), f2bf(v.w) };
      *(u16x4*)&xb[r][c4 * 4] = o4;
    }
#pragma unroll
    for (int i = 0; i < 8; i++) {          // W 128x64 fp32 -> wt[n][k] bf16
      int idx = t + i * 256, k = idx >> 4, n4 = idx & 15;
      float4 v = *(const float4*)&W[k * O + n4 * 4];
      wt[n4 * 4 + 0][k] = f2bf(v.x);
      wt[n4 * 4 + 1][k] = f2bf(v.y);
      wt[n4 * 4 + 2][k] = f2bf(v.z);
      wt[n4 * 4 + 3][k] = f2bf(v.w);
    }
    __syncthreads();

    const int w = t >> 6, l = t & 63;
    const int lm = l & 15, lg = l >> 4;
    const f32x4 z4 = {0.f, 0.f, 0.f, 0.f};
    bf16x8 af[4];
#pragma unroll
    for (int kc = 0; kc < 4; kc++)
      af[kc] = *(const bf16x8*)&xb[w * 16 + lm][kc * 32 + lg * 8];
    f32x4 acc[4];
#pragma unroll
    for (int ct = 0; ct < 4; ct++) {
      acc[ct] = z4;
#pragma unroll
      for (int kc = 0; kc < 4; kc++) {
        bf16x8 bfr = *(const bf16x8*)&wt[ct * 16 + lm][kc * 32 + lg * 8];
        acc[ct] = __builtin_amdgcn_mfma_f32_16x16x32_bf16(af[kc], bfr, acc[ct], 0, 0, 0);
      }
    }

    const int orow = brow + w * 16 + lg * 4;
    if (which == 0) {
      u16* dst = Q + h * N * O;
#pragma unroll
      for (int ct = 0; ct < 4; ct++)
#pragma unroll
        for (int r = 0; r < 4; r++)
          dst[(orow + r) * O + ct * 16 + lm] = f2bf(acc[ct][r] * QSCALE);
    } else if (which == 1) {
      u16* dst = K + h * N * O;
#pragma unroll
      for (int ct = 0; ct < 4; ct++)
#pragma unroll
        for (int r = 0; r < 4; r++)
          dst[(orow + r) * O + ct * 16 + lm] = f2bf(acc[ct][r]);
    } else {
      u16* dst = Vt + h * O * N;
#pragma unroll
      for (int ct = 0; ct < 4; ct++) {
        u16x4 v4 = { f2bf(acc[ct][0]), f2bf(acc[ct][1]),
                     f2bf(acc[ct][2]), f2bf(acc[ct][3]) };
        *(u16x4*)&dst[(size_t)(ct * 16 + lm) * N + orow] = v4;
      }
    }
  } else {
    // ---- mask ----
    int n = (b - 1792) * 256 + t;
    const float4* xr = (const float4*)(x + n * F);
    float s = 0.f;
#pragma unroll
    for (int i = 0; i < F / 4; i++) {
      float4 v = xr[i];
      s += fabsf(v.x) + fabsf(v.y) + fabsf(v.z) + fabsf(v.w);
    }
    rmask[n] = (s != 0.f) ? 1.f : 0.f;
  }
}

// ---------------------------------------------------------------------------
// Fused masked attention — swapped QK^T (R16-verified math) with THICK WAVES:
// each wave owns 32 q-rows via two q-sets (A: rows lm, B: rows 16+lm), and
// the K/V ds_reads are SHARED between both sets -> LDS reads + address VALU
// per element halve. grid (N/128, H, NZ=4), block 512 = 4 rg x 2 hc.
// Per iter: 64-key tile per hc (NT=8 iters over a 1024-key z-slice).
// sigma(tt,i) = 32(tt>>1)+8(i>>2)+4(tt&1)+(i&3) key permutation keeps P
// lane-local for PV (zero LDS round-trip). Swizzle sw_idx(row) =
// (row&3)|(((row>>3)&1)<<2) on BOTH staging source and ds_read (rule #21).
// Row-sums via ones-MFMA. Partials: Opart bf16 [NZ][H][N][O], Spart f32.
// LDS = kv 64KB + Ss2 1KB -> 2 blocks/CU (16 waves/CU, unchanged).
// ---------------------------------------------------------------------------
__global__ __launch_bounds__(512, 4) void attn_kernel(
    const u64* __restrict__ bits, const u16* __restrict__ Qg,
    const u16* __restrict__ Kg, const u16* __restrict__ Vtg,
    u16* __restrict__ Opart, float* __restrict__ Spart) {
  __shared__ __align__(16) char kv[2][4][8192];   // [buf][K0,K1,V0,V1][64x128B]
  __shared__ float Ss2[8][32];                    // per-wave row-sums (2 q-sets)

  const int tid = threadIdx.x;
  const int w = tid >> 6, l = tid & 63;
  const int lm = l & 15, lg = l >> 4;
  const int rg = w >> 1, hc = w & 1;     // row-group 0..3 (32 rows), col-half
  const int h = blockIdx.y;
  const int z = blockIdx.z;              // key slice 0..3 (1024 keys each)
  const int R0 = blockIdx.x * 128;
  const int WR0 = R0 + rg * 32;          // this wave's 32 Q-rows
  const int CB0 = z * 1024;              // this block's key base

  const char* Kb = (const char*)(Kg + h * N * O);    // 128B per key-row
  const char* Vb = (const char*)(Vtg + h * O * N);   // 8KB per o-row
  const u64* bblk = bits + (size_t)WR0 * NW;

  // staging: lane fills LDS slot (row=w*8+(l>>3), col=(l&7)*16) linearly;
  // global source column inverse-swizzled with sw_idx(row).
  const int srow = w * 8 + (l >> 3);
  const int ssw = (((srow & 3) | (((srow >> 3) & 1) << 2)) << 4);
  const int scol = ((l & 7) * 16) ^ ssw;

  const int krow_base = (lm & 3) + 8 * (lm >> 2);
  const int ksw = (lm & 7) << 4;
  const int vsw = (((lm & 3) | (((lm >> 3) & 1) << 2)) << 4);

  // Q fragments for both q-sets (B-operand: col=lm=qrow, k=lg*8+j)
  const u16* Qh = Qg + h * N * O;
  bf16x8 qa0 = *(const bf16x8*)&Qh[(WR0 + lm) * O + lg * 8];
  bf16x8 qa1 = *(const bf16x8*)&Qh[(WR0 + lm) * O + 32 + lg * 8];
  bf16x8 qb0 = *(const bf16x8*)&Qh[(WR0 + 16 + lm) * O + lg * 8];
  bf16x8 qb1 = *(const bf16x8*)&Qh[(WR0 + 16 + lm) * O + 32 + lg * 8];

  bf16x8 ones;
#pragma unroll
  for (int i = 0; i < 8; i++) ones[i] = (short)0x3F80;

  f32x4 oaccA[4], oaccB[4];
  f32x4 laccA = {0.f, 0.f, 0.f, 0.f}, laccB = {0.f, 0.f, 0.f, 0.f};
#pragma unroll
  for (int i = 0; i < 4; i++) {
    oaccA[i] = (f32x4){0.f, 0.f, 0.f, 0.f};
    oaccB[i] = (f32x4){0.f, 0.f, 0.f, 0.f};
  }
  const f32x4 zero4 = {0.f, 0.f, 0.f, 0.f};

  auto STAGE = [&](int b, int t) {
    __builtin_amdgcn_global_load_lds(
        (const u32*)(Kb + (size_t)(CB0 + 0 * 512 + t * 64 + srow) * 128 + scol),
        (u32*)&kv[b][0][w * 1024], 16, 0, 0);
    __builtin_amdgcn_global_load_lds(
        (const u32*)(Kb + (size_t)(CB0 + 1 * 512 + t * 64 + srow) * 128 + scol),
        (u32*)&kv[b][1][w * 1024], 16, 0, 0);
    __builtin_amdgcn_global_load_lds(
        (const u32*)(Vb + (size_t)srow * (N * 2) + (CB0 + 0 * 512 + t * 64) * 2 + scol),
        (u32*)&kv[b][2][w * 1024], 16, 0, 0);
    __builtin_amdgcn_global_load_lds(
        (const u32*)(Vb + (size_t)srow * (N * 2) + (CB0 + 1 * 512 + t * 64) * 2 + scol),
        (u32*)&kv[b][3][w * 1024], 16, 0, 0);
  };

  STAGE(0, 0);
  __syncthreads();

  int b = 0;
#pragma unroll 1
  for (int t = 0; t < NT; ++t) {
    if (t + 1 < NT) STAGE(b ^ 1, t + 1);   // prefetch next tile (other buffer)

    const int widx = z * 16 + hc * NT + t;

    // bits: one word per lane per q-set
    u64 wordA = bblk[lm * NW + widx];
    u64 wordB = bblk[(16 + lm) * NW + widx];
    u64 wA = wordA >> (8 * lg);
    u64 wB = wordB >> (8 * lg);

    // ---- S^T = mfma(K, Q) for both q-sets, sharing the K reads ----
    const char* Kt = &kv[b][hc][0];
    f32x4 sA[4], sB[4];
    __builtin_amdgcn_s_setprio(1);
#pragma unroll
    for (int tt = 0; tt < 4; tt++) {
      const int row = krow_base + 4 * (tt & 1) + 32 * (tt >> 1);
      bf16x8 kb0 = *(const bf16x8*)(Kt + row * 128 + ((lg * 16) ^ ksw));
      bf16x8 kb1 = *(const bf16x8*)(Kt + row * 128 + ((lg * 16 + 64) ^ ksw));
      f32x4 t0 = __builtin_amdgcn_mfma_f32_16x16x32_bf16(kb0, qa0, zero4, 0, 0, 0);
      sA[tt] = __builtin_amdgcn_mfma_f32_16x16x32_bf16(kb1, qa1, t0, 0, 0, 0);
      f32x4 t1 = __builtin_amdgcn_mfma_f32_16x16x32_bf16(kb0, qb0, zero4, 0, 0, 0);
      sB[tt] = __builtin_amdgcn_mfma_f32_16x16x32_bf16(kb1, qb1, t1, 0, 0, 0);
    }
    __builtin_amdgcn_s_setprio(0);

    // ---- P = adj ? 2^(max(s,0.2s)) : 0 — in registers, both sets ----
    bf16x8 paA0, paA1, paB0, paB1;
    {
      float pv[4][4];
#pragma unroll
      for (int tt = 0; tt < 4; tt++)
#pragma unroll
        for (int r = 0; r < 4; r++) {
          unsigned bit = (unsigned)(wA >> (4 * (tt & 1) + 32 * (tt >> 1) + r)) & 1u;
          float sv = sA[tt][r];
          float lv = fmaxf(sv, 0.2f * sv);
          pv[tt][r] = bit ? exp2_hw(lv) : 0.f;
        }
#pragma unroll
      for (int r = 0; r < 4; r++) {
        paA0[r]     = (short)f2bf(pv[0][r]);
        paA0[4 + r] = (short)f2bf(pv[1][r]);
        paA1[r]     = (short)f2bf(pv[2][r]);
        paA1[4 + r] = (short)f2bf(pv[3][r]);
      }
    }
    {
      float pv[4][4];
#pragma unroll
      for (int tt = 0; tt < 4; tt++)
#pragma unroll
        for (int r = 0; r < 4; r++) {
          unsigned bit = (unsigned)(wB >> (4 * (tt & 1) + 32 * (tt >> 1) + r)) & 1u;
          float sv = sB[tt][r];
          float lv = fmaxf(sv, 0.2f * sv);
          pv[tt][r] = bit ? exp2_hw(lv) : 0.f;
        }
#pragma unroll
      for (int r = 0; r < 4; r++) {
        paB0[r]     = (short)f2bf(pv[0][r]);
        paB0[4 + r] = (short)f2bf(pv[1][r]);
        paB1[r]     = (short)f2bf(pv[2][r]);
        paB1[4 + r] = (short)f2bf(pv[3][r]);
      }
    }

    // ---- O^T += mfma(V, P) for both sets, sharing the V reads ----
    const char* Vt_ = &kv[b][2 + hc][0];
    __builtin_amdgcn_s_setprio(1);
#pragma unroll
    for (int ot = 0; ot < 4; ot++) {
      const int o = ot * 16 + lm;
      bf16x8 vb0 = *(const bf16x8*)(Vt_ + o * 128 + ((lg * 16) ^ vsw));
      bf16x8 vb1 = *(const bf16x8*)(Vt_ + o * 128 + ((lg * 16 + 64) ^ vsw));
      oaccA[ot] = __builtin_amdgcn_mfma_f32_16x16x32_bf16(vb0, paA0, oaccA[ot], 0, 0, 0);
      oaccA[ot] = __builtin_amdgcn_mfma_f32_16x16x32_bf16(vb1, paA1, oaccA[ot], 0, 0, 0);
      oaccB[ot] = __builtin_amdgcn_mfma_f32_16x16x32_bf16(vb0, paB0, oaccB[ot], 0, 0, 0);
      oaccB[ot] = __builtin_amdgcn_mfma_f32_16x16x32_bf16(vb1, paB1, oaccB[ot], 0, 0, 0);
    }
    laccA = __builtin_amdgcn_mfma_f32_16x16x32_bf16(ones, paA0, laccA, 0, 0, 0);
    laccA = __builtin_amdgcn_mfma_f32_16x16x32_bf16(ones, paA1, laccA, 0, 0, 0);
    laccB = __builtin_amdgcn_mfma_f32_16x16x32_bf16(ones, paB0, laccB, 0, 0, 0);
    laccB = __builtin_amdgcn_mfma_f32_16x16x32_bf16(ones, paB1, laccB, 0, 0, 0);
    __builtin_amdgcn_s_setprio(0);

    __syncthreads();   // drains prefetch + protects buffer flip
    b ^= 1;
  }

  // ---- merge the 2 hc halves in LDS (Om2 aliases kv = exactly 64KB;
  // barrier-safe: writes happen after the final loop barrier). ----
  float (*Om2)[128][64] = (float (*)[128][64])&kv[0][0][0];  // 2*128*64*4 = 64KB
#pragma unroll
  for (int ot = 0; ot < 4; ot++) {
    *(f32x4*)&Om2[hc][rg * 32 + lm][ot * 16 + lg * 4] = oaccA[ot];
    *(f32x4*)&Om2[hc][rg * 32 + 16 + lm][ot * 16 + lg * 4] = oaccB[ot];
  }
  if (lg == 0) {
    Ss2[w][lm] = laccA[0];
    Ss2[w][16 + lm] = laccB[0];
  }
  __syncthreads();

  // ---- write partials: Opart bf16 [z][h][row][col], Spart f32 [z][h][row] ----
#pragma unroll
  for (int rr = 0; rr < 2; rr++) {
    const int row = rr * 64 + (tid >> 3);   // 0..127
    const int c0 = (tid & 7) * 8;           // 0..56
    const int grow = R0 + row;
    u16* op = &Opart[(((size_t)z * H + h) * N + grow) * O + c0];
    u16x4 v0 = { f2bf(Om2[0][row][c0 + 0] + Om2[1][row][c0 + 0]),
                 f2bf(Om2[0][row][c0 + 1] + Om2[1][row][c0 + 1]),
                 f2bf(Om2[0][row][c0 + 2] + Om2[1][row][c0 + 2]),
                 f2bf(Om2[0][row][c0 + 3] + Om2[1][row][c0 + 3]) };
    u16x4 v1 = { f2bf(Om2[0][row][c0 + 4] + Om2[1][row][c0 + 4]),
                 f2bf(Om2[0][row][c0 + 5] + Om2[1][row][c0 + 5]),
                 f2bf(Om2[0][row][c0 + 6] + Om2[1][row][c0 + 6]),
                 f2bf(Om2[0][row][c0 + 7] + Om2[1][row][c0 + 7]) };
    *(u16x4*)&op[0] = v0;
    *(u16x4*)&op[4] = v1;
    if ((tid & 7) == 0) {
      const int rg2 = row >> 5, ri = row & 31;
      Spart[((size_t)z * H + h) * N + grow] = Ss2[rg2 * 2 + 0][ri] + Ss2[rg2 * 2 + 1][ri];
    }
  }
}

// ---------------------------------------------------------------------------
// Merge the NZ z-slices: out = relu((Σ O_z)/(Σ S_z)) * rowmask.
// ---------------------------------------------------------------------------
__global__ __launch_bounds__(256) void merge_kernel(
    const u16* __restrict__ Opart, const float* __restrict__ Spart,
    const float* __restrict__ rowmask, float* __restrict__ out) {
  const int h = blockIdx.y;
  const int idx = blockIdx.x * 256 + threadIdx.x;
  const int row = idx >> 4, c0 = (idx & 15) * 4;
  float S = 0.f;
#pragma unroll
  for (int z = 0; z < NZ; z++) S += Spart[((size_t)z * H + h) * N + row];
  float inv = (S > 0.f) ? 1.f / S : 0.f;
  float rm = rowmask[row];
  float a0 = 0.f, a1 = 0.f, a2 = 0.f, a3 = 0.f;
#pragma unroll
  for (int z = 0; z < NZ; z++) {
    u16x4 v = *(const u16x4*)&Opart[(((size_t)z * H + h) * N + row) * O + c0];
    a0 += bf2f(v[0]); a1 += bf2f(v[1]); a2 += bf2f(v[2]); a3 += bf2f(v[3]);
  }
  float4 r;
  r.x = fmaxf(a0 * inv, 0.f) * rm;
  r.y = fmaxf(a1 * inv, 0.f) * rm;
  r.z = fmaxf(a2 * inv, 0.f) * rm;
  r.w = fmaxf(a3 * inv, 0.f) * rm;
  *(float4*)&out[(size_t)row * (H * O) + h * O + c0] = r;
}

extern "C" void kernel_launch(void* const* d_in, const int* in_sizes, int n_in,
                              void* d_out, int out_size, void* d_ws, size_t ws_size,
                              hipStream_t stream) {
  const float* x   = (const float*)d_in[0];  // h [1,4096,128]
  const float* adj = (const float*)d_in[1];  // a [1,4096,4096]
  const float* wv  = (const float*)d_in[2];  // kernel      -> V
  const float* wq  = (const float*)d_in[3];  // attn_kernel -> Q (f_self)
  const float* wk  = (const float*)d_in[4];  // attn_kernel2-> K (f_other)
  float* out = (float*)d_out;

  u16* Q  = (u16*)d_ws;                     // [4][4096][64] bf16  (2 MB)
  u16* K  = Q + H * N * O;                  // [4][4096][64] bf16  (2 MB)
  u16* Vt = K + H * N * O;                  // [4][64][4096] bf16  (2 MB)
  float* rmask = (float*)(Vt + H * N * O);  // [4096] f32 (16 KB)
  u64* bits = (u64*)(rmask + N);            // [4096][64] u64 (2 MB)
  u16* Opart = (u16*)(bits + (size_t)N * NW);       // [4][4][4096][64] bf16 (8 MB)
  float* Spart = (float*)(Opart + (size_t)NZ * H * N * O);  // [4][4][4096] f32 (256 KB)

  prep_kernel<<<dim3(1808), 256, 0, stream>>>(x, adj, wv, wq, wk, Q, K, Vt, rmask, bits);
  attn_kernel<<<dim3(N / 128, H, NZ), 512, 0, stream>>>(bits, Q, K, Vt, Opart, Spart);
  merge_kernel<<<dim3(N * O / 4 / 256, H), 256, 0, stream>>>(Opart, Spart, rmask, out);
}